// Round 4
// baseline (287.943 us; speedup 1.0000x reference)
//
#include <hip/hip_runtime.h>
#include <stdint.h>

typedef __attribute__((ext_vector_type(8))) short short8;
typedef __attribute__((ext_vector_type(4))) float f32x4;
typedef __attribute__((ext_vector_type(8))) float f32x8;
typedef __bf16 bf16x8_t __attribute__((ext_vector_type(8)));

#define NN       784           // 28*28
#define NKT      25            // K tiles of 32 (784 padded to 800)
#define BM       64            // batch rows per block
#define NFRAG    49            // n-fragments of 16 cols (49*16 = 784)
#define FRAG_U16 512           // ushorts per fragment (16 rows x 32 k)
#define TILE_U16 (NFRAG * FRAG_U16)   // 25088 ushorts per K-tile

__device__ __forceinline__ unsigned short f2bf(float f) {
  unsigned int u = __float_as_uint(f);
  return (unsigned short)((u + 0x7FFFu + ((u >> 16) & 1u)) >> 16);  // RNE, finite inputs
}

__device__ __forceinline__ short8 cvt8(f32x4 lo, f32x4 hi) {
  f32x8 f = {lo.x, lo.y, lo.z, lo.w, hi.x, hi.y, hi.z, hi.w};
  bf16x8_t b = __builtin_convertvector(f, bf16x8_t);   // v_cvt_pk_bf16_f32 (RNE)
  return __builtin_bit_cast(short8, b);
}

// Bpack[t][nf] = one MFMA B-fragment, 1KB contiguous.
// In-frag ushort index for (row rl = n&15, k kk): lane = (kk>>3)*16 + rl,
// idx = lane*8 + (kk&7).  Value = weight[n] * W[n][j=t*32+kk], 0 for j>=784.
__global__ void build_w_kernel(const float* __restrict__ pos2d,
                               const float* __restrict__ weight,
                               const float* __restrict__ ep,
                               unsigned short* __restrict__ Bpack) {
  int idx = blockIdx.x * 256 + threadIdx.x;   // 0 .. 25*784*32-1
  int kk   = idx & 31;
  int rest = idx >> 5;                        // t*784 + n
  int n = rest % NN;
  int t = rest / NN;
  int j = t * 32 + kk;
  float val = 0.f;
  if (j < NN) {
    int a = n / 28, b = n - a * 28;           // output cell (row n of W)
    float px = pos2d[2 * j + 0];
    float py = pos2d[2 * j + 1];
    float dx = (float)b - px;
    float dy = (float)a - py;
    float d2 = __fadd_rn(__fmul_rn(dx, dx), __fmul_rn(dy, dy));  // match np (no fma)
    if (d2 < 9.0f) {
      float en = fminf(ep[j], 0.f);
      val = expf(en * d2) * weight[n];
    }
  }
  int nf = n >> 4, rl = n & 15;
  int dst = t * TILE_U16 + nf * FRAG_U16 + ((kk >> 3) * 16 + rl) * 8 + (kk & 7);
  Bpack[dst] = f2bf(val);
}

// No LDS, no barriers. 8 waves; wave w owns n-frags {w, w+8, ..., w+40} (+48 for w==0)
// and all 4 m-frags. B frags stream from L2 (frag-contiguous, coalesced dwordx4);
// A frags stream from x (L1-shared across waves), converted fp32->bf16 in-register.
__global__ __launch_bounds__(512, 2)
void gemm_kernel(const float* __restrict__ x,
                 const unsigned short* __restrict__ Bpack,
                 float* __restrict__ out) {
  const int tid  = threadIdx.x;
  const int wave = tid >> 6;
  const int lane = tid & 63;
  const int m0   = blockIdx.x * BM;
  const int rl   = lane & 15;       // row-in-frag / col-in-frag
  const int ch   = lane >> 4;       // k-chunk (8 consecutive k)

  bool fok[7];
  const unsigned short* bbase[7];
  #pragma unroll
  for (int f = 0; f < 7; ++f) {
    int fid = wave + f * 8;
    fok[f] = (fid < NFRAG);
    bbase[f] = Bpack + (fok[f] ? fid : 0) * FRAG_U16 + lane * 8;
  }
  const float* abase[4];
  #pragma unroll
  for (int mf = 0; mf < 4; ++mf)
    abase[mf] = x + (size_t)(m0 + mf * 16 + rl) * NN;

  f32x4 acc[7][4];
  #pragma unroll
  for (int f = 0; f < 7; ++f)
    #pragma unroll
    for (int mf = 0; mf < 4; ++mf) acc[f][mf] = (f32x4){0.f, 0.f, 0.f, 0.f};

  f32x4 alo[4], ahi[4];
  short8 b0[7], b1[7];

  // t = 0 loads
  #pragma unroll
  for (int mf = 0; mf < 4; ++mf) {
    int k = ch * 8;
    alo[mf] = *(const f32x4*)(abase[mf] + k);
    ahi[mf] = *(const f32x4*)(abase[mf] + k + 4);
  }
  #pragma unroll
  for (int f = 0; f < 7; ++f)
    if (fok[f]) b0[f] = *(const short8*)(bbase[f]);

#define STEP(T, BIN, BOUT, PREF)                                              \
  {                                                                           \
    short8 afr[4];                                                            \
    _Pragma("unroll")                                                         \
    for (int mf = 0; mf < 4; ++mf) afr[mf] = cvt8(alo[mf], ahi[mf]);          \
    if (PREF) {                                                               \
      _Pragma("unroll")                                                       \
      for (int mf = 0; mf < 4; ++mf) {                                        \
        int k = ((T) + 1) * 32 + ch * 8;                                      \
        if (k > 776) k = 776;   /* tail: valid data x B==0 -> exact 0 */      \
        alo[mf] = *(const f32x4*)(abase[mf] + k);                             \
        ahi[mf] = *(const f32x4*)(abase[mf] + k + 4);                         \
      }                                                                       \
      _Pragma("unroll")                                                       \
      for (int f = 0; f < 7; ++f)                                             \
        if (fok[f])                                                           \
          BOUT[f] = *(const short8*)(bbase[f] + (size_t)((T) + 1) * TILE_U16);\
    }                                                                         \
    _Pragma("unroll")                                                         \
    for (int f = 0; f < 7; ++f)                                               \
      if (fok[f]) {                                                           \
        _Pragma("unroll")                                                     \
        for (int mf = 0; mf < 4; ++mf)                                        \
          acc[f][mf] = __builtin_amdgcn_mfma_f32_16x16x32_bf16(               \
              afr[mf], BIN[f], acc[f][mf], 0, 0, 0);                          \
      }                                                                       \
  }

  for (int t = 0; t < 24; t += 2) {
    STEP(t,     b0, b1, true);
    STEP(t + 1, b1, b0, true);
  }
  STEP(24, b0, b1, false);
#undef STEP

  // Epilogue: C frag mapping col = lane&15, row = (lane>>4)*4 + reg
  #pragma unroll
  for (int f = 0; f < 7; ++f) {
    if (fok[f]) {
      int col = (wave + f * 8) * 16 + rl;
      #pragma unroll
      for (int mf = 0; mf < 4; ++mf) {
        int row = m0 + mf * 16 + ch * 4;
        f32x4 a = acc[f][mf];
        out[(size_t)(row + 0) * NN + col] = a.x;
        out[(size_t)(row + 1) * NN + col] = a.y;
        out[(size_t)(row + 2) * NN + col] = a.z;
        out[(size_t)(row + 3) * NN + col] = a.w;
      }
    }
  }
}

extern "C" void kernel_launch(void* const* d_in, const int* in_sizes, int n_in,
                              void* d_out, int out_size, void* d_ws, size_t ws_size,
                              hipStream_t stream) {
  const float* x      = (const float*)d_in[0];
  const float* pos2d  = (const float*)d_in[1];
  const float* weight = (const float*)d_in[2];
  const float* ep     = (const float*)d_in[3];
  float* out          = (float*)d_out;
  unsigned short* Bpack = (unsigned short*)d_ws;        // 25*49*512*2 = 1,254,400 B

  int batch = in_sizes[0] / NN;                         // 65536

  build_w_kernel<<<dim3((NKT * NN * 32) / 256), dim3(256), 0, stream>>>(pos2d, weight, ep, Bpack);
  gemm_kernel<<<dim3(batch / BM), dim3(512), 0, stream>>>(x, Bpack, out);
}

// Round 5
// 155.140 us; speedup vs baseline: 1.8560x; 1.8560x over previous
//
#include <hip/hip_runtime.h>
#include <stdint.h>

typedef __attribute__((ext_vector_type(8))) short short8;
typedef __attribute__((ext_vector_type(4))) float f32x4;
typedef __attribute__((ext_vector_type(8))) float f32x8;
typedef __bf16 bf16x8_t __attribute__((ext_vector_type(8)));

#define NN     784             // 28*28
#define BM     64              // images per block
#define NA     28              // output rows (a)
#define NSLOT  8               // K-slots of 32 per a (256-wide window covers the 196 band)
#define FRAG_U16 512           // ushorts per 16x32 B-fragment
#define ABYTES  (NSLOT * 2 * FRAG_U16 * 2)   // 16384 B of B-table per a

__device__ __forceinline__ unsigned short f2bf(float f) {
  unsigned int u = __float_as_uint(f);
  return (unsigned short)((u + 0x7FFFu + ((u >> 16) & 1u)) >> 16);  // RNE, finite inputs
}

__device__ __forceinline__ short8 cvt8(f32x4 lo, f32x4 hi) {
  f32x8 f = {lo.x, lo.y, lo.z, lo.w, hi.x, hi.y, hi.z, hi.w};
  bf16x8_t b = __builtin_convertvector(f, bf16x8_t);   // v_cvt_pk_bf16_f32 (RNE)
  return __builtin_bit_cast(short8, b);
}

// First stored k-slot for output row a: 32-aligned window start covering
// k in [28(a-3), 28(a+4)), clamped to slots [0, 17] so slots s=0..7 stay in [0,24].
__device__ __forceinline__ int slot0(int a) {
  int t = 28 * a - 84;
  if (t < 0) t = 0;
  t >>= 5;                      // floor(t/32), t >= 0
  if (t > 17) t = 17;
  return t;
}

// Bpack[a][s][nf] = 1KB MFMA B-fragment (16 cols x 32 k), frag-contiguous.
// In-frag u16 index for (col rl, k kk): ((kk>>3)*16 + rl)*8 + (kk&7).
// Value = weight[a*28+ncol] * W[a*28+ncol][kglob], 0 outside grid/band.
__global__ void build_w_kernel(const float* __restrict__ pos2d,
                               const float* __restrict__ weight,
                               const float* __restrict__ ep,
                               unsigned short* __restrict__ Bpack) {
  int idx = blockIdx.x * 256 + threadIdx.x;   // 0 .. 28*8*2*512-1
  int u    = idx & 511;
  int frag = idx >> 9;          // ((a*8 + s)*2 + nf)
  int nf = frag & 1;
  int s  = (frag >> 1) & 7;
  int a  = frag >> 4;
  int j8   = u & 7;
  int lane = u >> 3;
  int rl = lane & 15;
  int ch = lane >> 4;
  int kk = ch * 8 + j8;                        // 0..31
  int kglob = (slot0(a) + s) * 32 + kk;
  int ncol  = nf * 16 + rl;
  float val = 0.f;
  if (ncol < 28 && kglob < NN) {
    float px = pos2d[2 * kglob + 0];
    float py = pos2d[2 * kglob + 1];
    float dx = (float)ncol - px;
    float dy = (float)a - py;
    float d2 = __fadd_rn(__fmul_rn(dx, dx), __fmul_rn(dy, dy));  // match np (no fma)
    if (d2 < 9.0f) {
      float en = fminf(ep[kglob], 0.f);
      val = expf(en * d2) * weight[a * 28 + ncol];
    }
  }
  Bpack[idx] = f2bf(val);
}

// Banded GEMM: out[b, a*28+c] = sum_k x[b,k] * W[a*28+c, k], k in a 256-window.
// 4 waves x 16 images; each lane keeps its whole x row in registers (bf16);
// B-tile (16KB per a) double-buffered in LDS via global_load_lds.
__global__ __launch_bounds__(256, 3)
void gemm_kernel(const float* __restrict__ x,
                 const unsigned short* __restrict__ Bpack,
                 float* __restrict__ out) {
  __shared__ unsigned short Blds[2][NSLOT * 2 * FRAG_U16];   // 2 x 16 KB

  const int tid  = threadIdx.x;
  const int wave = tid >> 6;
  const int lane = tid & 63;
  const int rl   = lane & 15;       // image-row within frag / col within B-frag
  const int ch   = lane >> 4;       // k-chunk of 8
  const int m0   = blockIdx.x * BM;

  auto stage = [&](int buf, int a) {
    const char* src = (const char*)Bpack + (size_t)a * ABYTES + tid * 16;
    char* dst = (char*)&Blds[buf][0] + tid * 16;
    #pragma unroll
    for (int i = 0; i < 4; ++i)
      __builtin_amdgcn_global_load_lds(
          (const __attribute__((address_space(1))) uint32_t*)(src + i * 4096),
          (__attribute__((address_space(3))) uint32_t*)(uintptr_t)(dst + i * 4096),
          16, 0, 0);
  };

  stage(0, 0);    // hide under the x-row load burst

  // Load this lane's x row (image m0 + wave*16 + rl), k-phase ch, into 25 short8s.
  const float* xrow = x + (size_t)(m0 + wave * 16 + rl) * NN;
  short8 xr[25];
  #pragma unroll
  for (int t = 0; t < 25; ++t) {
    int k = t * 32 + ch * 8;
    f32x4 lo = (f32x4){0.f, 0.f, 0.f, 0.f};
    f32x4 hi = (f32x4){0.f, 0.f, 0.f, 0.f};
    if (k + 7 < NN) {                 // only t==24, ch>=2 excluded (B is 0 there)
      lo = *(const f32x4*)(xrow + k);
      hi = *(const f32x4*)(xrow + k + 4);
    }
    xr[t] = cvt8(lo, hi);
  }
  __syncthreads();

  const size_t orow = (size_t)(m0 + wave * 16 + ch * 4) * NN;

  #pragma unroll
  for (int a = 0; a < NA; ++a) {
    const int cur = a & 1;
    if (a + 1 < NA) stage(cur ^ 1, a + 1);

    const int t0 = slot0(a);
    f32x4 acc0 = (f32x4){0.f, 0.f, 0.f, 0.f};
    f32x4 acc1 = (f32x4){0.f, 0.f, 0.f, 0.f};

    #pragma unroll
    for (int s = 0; s < NSLOT; ++s) {
      short8 b0 = *(const short8*)((char*)&Blds[cur][0] + (s * 2 + 0) * 1024 + lane * 16);
      short8 b1 = *(const short8*)((char*)&Blds[cur][0] + (s * 2 + 1) * 1024 + lane * 16);
      short8 af = xr[t0 + s];
      acc0 = __builtin_amdgcn_mfma_f32_16x16x32_bf16(af, b0, acc0, 0, 0, 0);
      acc1 = __builtin_amdgcn_mfma_f32_16x16x32_bf16(af, b1, acc1, 0, 0, 0);
    }

    // C frag: col = lane&15, row = (lane>>4)*4 + reg.  out col = nf*16 + rl (< 28).
    {
      size_t base = orow + a * 28 + rl;
      out[base + 0 * NN] = acc0.x;
      out[base + 1 * NN] = acc0.y;
      out[base + 2 * NN] = acc0.z;
      out[base + 3 * NN] = acc0.w;
      if (rl < 12) {
        size_t base1 = base + 16;
        out[base1 + 0 * NN] = acc1.x;
        out[base1 + 1 * NN] = acc1.y;
        out[base1 + 2 * NN] = acc1.z;
        out[base1 + 3 * NN] = acc1.w;
      }
    }
    __syncthreads();
  }
}

extern "C" void kernel_launch(void* const* d_in, const int* in_sizes, int n_in,
                              void* d_out, int out_size, void* d_ws, size_t ws_size,
                              hipStream_t stream) {
  const float* x      = (const float*)d_in[0];
  const float* pos2d  = (const float*)d_in[1];
  const float* weight = (const float*)d_in[2];
  const float* ep     = (const float*)d_in[3];
  float* out          = (float*)d_out;
  unsigned short* Bpack = (unsigned short*)d_ws;        // 28*8*2*512*2 = 458,752 B

  int batch = in_sizes[0] / NN;                         // 65536

  build_w_kernel<<<dim3((NA * NSLOT * 2 * FRAG_U16) / 256), dim3(256), 0, stream>>>(
      pos2d, weight, ep, Bpack);
  gemm_kernel<<<dim3(batch / BM), dim3(256), 0, stream>>>(x, Bpack, out);
}